// Round 1
// baseline (436.914 us; speedup 1.0000x reference)
//
#include <hip/hip_runtime.h>
#include <hip/hip_bf16.h>

typedef __bf16 bf16;
typedef __bf16 v8bf __attribute__((ext_vector_type(8)));
typedef __bf16 v4bf __attribute__((ext_vector_type(4)));
typedef float  v4f  __attribute__((ext_vector_type(4)));

#define DEVI __device__ __forceinline__

constexpr int Bc   = 4;
constexpr int Tc   = 2048;
constexpr int Dc   = 768;
constexpr int Hc   = 12;
constexpr int HDc  = 64;
constexpr int MLPc = 3072;
constexpr int QKVc = 2304;    // 3*D
constexpr int BTc  = Bc * Tc; // 8192 rows

DEVI float b2f(bf16 x) { return (float)x; }
DEVI bf16  f2b(float x) { return (bf16)x; }

// async global->LDS, 16B per lane; lds dest = wave-uniform base + lane*16
#define GLDS(gp, lp) __builtin_amdgcn_global_load_lds( \
    (const __attribute__((address_space(1))) void*)(gp), \
    (__attribute__((address_space(3))) void*)(lp), 16, 0, 0)

// ---------------------------------------------------------------- fp32 -> bf16 conversion (two arrays per dispatch)
__global__ __launch_bounds__(256) void cvt2_kernel(
    const float* __restrict__ s0, bf16* __restrict__ d0, int n0,
    const float* __restrict__ s1, bf16* __restrict__ d1)
{
    int i = blockIdx.x * 256 + threadIdx.x;
    const float* s; bf16* d; int j;
    if (i < n0) { s = s0; d = d0; j = i; }
    else        { s = s1; d = d1; j = i - n0; }
    float4 v = ((const float4*)s)[j];
    v4bf o = { f2b(v.x), f2b(v.y), f2b(v.z), f2b(v.w) };
    ((v4bf*)d)[j] = o;
}

// ---------------------------------------------------------------- LayerNorm (fp32 in, bf16 out)
__global__ __launch_bounds__(256) void ln_kernel(
    const float* __restrict__ x, const float* __restrict__ g,
    const float* __restrict__ bt, bf16* __restrict__ out)
{
    const int row = blockIdx.x;
    const int t = threadIdx.x;
    const float* xr = x + (size_t)row * Dc;
    float v[3];
    v[0] = xr[t];
    v[1] = xr[t + 256];
    v[2] = xr[t + 512];
    float s = v[0] + v[1] + v[2];
    float s2 = v[0]*v[0] + v[1]*v[1] + v[2]*v[2];
    #pragma unroll
    for (int off = 32; off > 0; off >>= 1) {
        s  += __shfl_down(s, off);
        s2 += __shfl_down(s2, off);
    }
    __shared__ float red[8];
    const int wave = t >> 6, lane = t & 63;
    if (lane == 0) { red[wave] = s; red[4 + wave] = s2; }
    __syncthreads();
    s  = red[0] + red[1] + red[2] + red[3];
    s2 = red[4] + red[5] + red[6] + red[7];
    const float mean = s * (1.0f / Dc);
    const float var  = s2 * (1.0f / Dc) - mean * mean;
    const float rstd = rsqrtf(var + 1e-5f);
    bf16* orow = out + (size_t)row * Dc;
    #pragma unroll
    for (int i = 0; i < 3; i++) {
        int c = t + i * 256;
        orow[c] = f2b((v[i] - mean) * rstd * g[c] + bt[c]);
    }
}

// ---------------------------------------------------------------- GEMM (C = A @ B^T + bias, fused epilogues)
// A: [M][lda] bf16 row-major; Bw: [N rows][ldb] bf16, K columns used.
// TN = 128 (4 waves of 64x64) or 64 (4 waves of 32x64).
// XCD stripe swizzle + XOR LDS swizzle. EPI_QKV (TN=128): split-store Q|K|Vt.
// Q columns are pre-scaled by log2(e)/8 so attention's exp2 needs no mul.
enum { EPI_QKV = 0, EPI_GELU_BF16 = 1, EPI_RESID_F32 = 2, EPI_ACC_F32 = 3 };

template <int EPI, int TN>
__global__ __launch_bounds__(256) void gemm_bt(
    const bf16* __restrict__ A, const bf16* __restrict__ Bw,
    const float* __restrict__ bias,
    bf16* __restrict__ Cb, float* __restrict__ Cf,
    const float* __restrict__ resf,
    int M, int N, int K, int lda, int ldb)
{
    constexpr int MI = (TN == 128) ? 4 : 2;      // 16-row blocks per wave (m)
    __shared__ __align__(16) bf16 sA[128 * 64];
    __shared__ __align__(16) bf16 sB[TN * 64];
    const int t = threadIdx.x, wave = t >> 6, lane = t & 63;
    const int moff = (TN == 128) ? (wave & 1) * 64 : wave * 32;
    const int noff = (TN == 128) ? (wave >> 1) * 64 : 0;
    // XCD stripe swizzle (ny divisible by 8 for all our shapes)
    const int nx = gridDim.x, ny = gridDim.y;
    const int bid = blockIdx.y * nx + blockIdx.x;
    const int xcd = bid & 7, kk = bid >> 3;
    const int m0 = (xcd * (ny >> 3) + kk / nx) * 128;
    const int n0 = (kk % nx) * TN;
    const bf16* Ag = A + (size_t)m0 * lda;
    const bf16* Bg = Bw + (size_t)n0 * ldb;

    v4f acc[MI][4];
    #pragma unroll
    for (int i = 0; i < MI; i++)
        #pragma unroll
        for (int j = 0; j < 4; j++) acc[i][j] = (v4f)(0.0f);

    for (int k0 = 0; k0 < K; k0 += 64) {
        // stage with XOR swizzle: LDS slot c holds global chunk (c&7)^(r&7)
        #pragma unroll
        for (int i = 0; i < 4; i++) {
            int c = i * 256 + t;
            int r = c >> 3, j = (c & 7) ^ (r & 7);
            GLDS(Ag + (size_t)r * lda + k0 + j * 8,
                 &sA[(i * 256 + wave * 64) * 8]);
        }
        #pragma unroll
        for (int i = 0; i < TN / 32; i++) {
            int c = i * 256 + t;
            int r = c >> 3, j = (c & 7) ^ (r & 7);
            GLDS(Bg + (size_t)r * ldb + k0 + j * 8,
                 &sB[(i * 256 + wave * 64) * 8]);
        }
        __syncthreads();
        #pragma unroll
        for (int ks = 0; ks < 2; ks++) {
            const int rq = lane >> 4, rl = lane & 15;
            v8bf a[MI], b[4];
            #pragma unroll
            for (int mi = 0; mi < MI; mi++) {
                const int row = moff + mi * 16 + rl;
                a[mi] = *(const v8bf*)&sA[row * 64 + ((ks * 4 + rq) ^ (row & 7)) * 8];
            }
            #pragma unroll
            for (int ni = 0; ni < 4; ni++) {
                const int row = noff + ni * 16 + rl;
                b[ni] = *(const v8bf*)&sB[row * 64 + ((ks * 4 + rq) ^ (row & 7)) * 8];
            }
            #pragma unroll
            for (int mi = 0; mi < MI; mi++)
                #pragma unroll
                for (int ni = 0; ni < 4; ni++)
                    acc[mi][ni] = __builtin_amdgcn_mfma_f32_16x16x32_bf16(
                        a[mi], b[ni], acc[mi][ni], 0, 0, 0);
        }
        __syncthreads();
    }

    const int rq = lane >> 4, cn = lane & 15;
    #pragma unroll
    for (int mi = 0; mi < MI; mi++)
        #pragma unroll
        for (int ni = 0; ni < 4; ni++) {
            const int col = n0 + noff + ni * 16 + cn;
            const float bv = bias ? bias[col] : 0.0f;
            if constexpr (EPI == EPI_QKV) {
                const int row0 = m0 + moff + mi * 16 + rq * 4;
                if (n0 < 2 * Dc) {
                    bf16* dst = Cb + (col < Dc ? 0 : (size_t)BTc * Dc);
                    const int cadj = col < Dc ? col : col - Dc;
                    const float qs = (col < Dc) ? 0.18033688011112042f : 1.0f;
                    #pragma unroll
                    for (int r = 0; r < 4; r++)
                        dst[(size_t)(row0 + r) * Dc + cadj] = f2b((acc[mi][ni][r] + bv) * qs);
                } else {
                    const int vcol = col - 2 * Dc;
                    const int hh = vcol >> 6, hd = vcol & 63;
                    const int bb = row0 >> 11, t0 = row0 & 2047;
                    v4bf pk;
                    #pragma unroll
                    for (int r = 0; r < 4; r++) pk[r] = f2b(acc[mi][ni][r] + bv);
                    *(v4bf*)(Cb + 2 * (size_t)BTc * Dc +
                             (((size_t)bb * Hc + hh) * HDc + hd) * Tc + t0) = pk;
                }
            } else {
                #pragma unroll
                for (int r = 0; r < 4; r++) {
                    const int row = m0 + moff + mi * 16 + rq * 4 + r;
                    const size_t idx = (size_t)row * N + col;
                    float vv = acc[mi][ni][r] + bv;
                    if constexpr (EPI == EPI_GELU_BF16) {
                        Cb[idx] = f2b(0.5f * vv * (1.0f + erff(vv * 0.70710678118f)));
                    } else if constexpr (EPI == EPI_RESID_F32) {
                        Cf[idx] = vv + resf[idx];
                    } else {  // EPI_ACC_F32: sequential RMW accumulate
                        Cf[idx] = vv + Cf[idx];
                    }
                }
            }
        }
}

// ---------------------------------------------------------------- Banded flash attention, v2
// No K-split: each of 4 waves owns a 16-row q-strip and walks the whole band.
// Per-wave accumulators are final -> zero merge epilogue, zero __syncthreads.
// S computed transposed via mfma(K, Q) so each lane holds 4 consecutive k for
// one q -> P packs to v4bf and stores with a single ds_write_b64 (was 4 scalar
// ds_write_u16). XOR chunk-swizzle keeps both b64 writes and b128 reads
// bank-uniform with an unpadded [16][64] per-wave P tile (8 KB LDS total).
// Q is pre-scaled by log2(e)/8 in the QKV epilogue; no-max softmax is exact
// (shift-invariant; exp2 clamp at 2^30, sum <= 513*2^30 fits fp32).
__global__ __launch_bounds__(256, 4) void attn_kernel(
    const bf16* __restrict__ Qb, const bf16* __restrict__ Kb,
    const bf16* __restrict__ Vt, bf16* __restrict__ o,
    const int* __restrict__ winp)
{
    const int bh = blockIdx.x, qt = blockIdx.y;
    const int b = bh / Hc, h = bh % Hc;
    const int q0 = qt * 64;
    const int win = *winp;
    const int t = threadIdx.x, wave = t >> 6, lane = t & 63;
    const int rq = lane >> 4, cn = lane & 15;
    const int qw0 = q0 + wave * 16;              // this wave's q-strip

    __shared__ __align__(16) bf16 sP[4][16 * 64];
    bf16* const sPw = &sP[wave][0];
    const int swz  = (cn & 7) << 1;              // XOR on 8B-chunk index (bit0 kept)
    const int prow = cn << 6;                    // q-row base, stride 64 elems = 128 B

    const bf16* qp  = Qb + ((size_t)b * Tc) * Dc + h * HDc;
    const bf16* kp  = Kb + ((size_t)b * Tc) * Dc + h * HDc;
    const bf16* vtp = Vt + (size_t)bh * HDc * Tc;

    // Q fragments hoisted once (B-operand: row = cn, k = ks*32 + rq*8)
    v8bf qf[2];
    #pragma unroll
    for (int ks = 0; ks < 2; ks++)
        qf[ks] = *(const v8bf*)(qp + (size_t)(qw0 + cn) * Dc + ks * 32 + rq * 8);

    v4f acc_o[4], acc_l = (v4f)(0.0f);
    #pragma unroll
    for (int nh = 0; nh < 4; nh++) acc_o[nh] = (v4f)(0.0f);
    v8bf vones;
    #pragma unroll
    for (int j = 0; j < 8; j++) vones[j] = f2b(1.0f);

    // key subtiles kb0 = q0 - win + s*64, constrained to [0, Tc-64]
    const int s_lo = (q0 >= win) ? 0 : ((win - q0 + 63) >> 6);
    const int kb_hi = min(Tc - 64, q0 + win);
    const int s_hi = (kb_hi - (q0 - win)) >> 6;          // inclusive

    for (int s = s_lo; s <= s_hi; s++) {
        const int kb0 = q0 - win + s * 64;               // in [0, Tc-64]

        // S^T = K @ Q^T : reg-block kb -> k rows kb*16+rq*4+r, q col = cn
        v4f sf[4];
        #pragma unroll
        for (int kb = 0; kb < 4; kb++) sf[kb] = (v4f)(0.0f);
        #pragma unroll
        for (int ks = 0; ks < 2; ks++) {
            const int kc = ks * 32 + rq * 8;
            v8bf kf[4];
            #pragma unroll
            for (int kb = 0; kb < 4; kb++)
                kf[kb] = *(const v8bf*)(kp + (size_t)(kb0 + kb * 16 + cn) * Dc + kc);
            #pragma unroll
            for (int kb = 0; kb < 4; kb++)
                sf[kb] = __builtin_amdgcn_mfma_f32_16x16x32_bf16(
                    kf[kb], qf[ks], sf[kb], 0, 0, 0);
        }

        // p = exp2(clamp(sT)); per-wave edge mask; 4 consecutive k -> one b64
        const bool need_mask = (kb0 + 63 - qw0 > win) || (qw0 + 15 - kb0 > win);
        const int qi = qw0 + cn;
        #pragma unroll
        for (int kb = 0; kb < 4; kb++) {
            v4bf pk;
            #pragma unroll
            for (int r = 0; r < 4; r++) {
                float tt = sf[kb][r];
                if (need_mask) {
                    int ki = kb0 + kb * 16 + rq * 4 + r;
                    int dd = qi - ki; dd = dd < 0 ? -dd : dd;
                    tt = (dd > win) ? -INFINITY : tt;
                }
                pk[r] = f2b(exp2f(fminf(tt, 30.0f)));   // masked -> 0
            }
            *(v4bf*)&sPw[prow + (((kb * 4 + rq) ^ swz) << 2)] = pk;
        }

        // O += P V ; l += P 1   (A-frag: q row = cn, k = ks*32 + rq*8)
        #pragma unroll
        for (int ks = 0; ks < 2; ks++) {
            const int kc = ks * 32 + rq * 8;
            v8bf pa = *(const v8bf*)&sPw[prow + (((ks * 8 + rq * 2) ^ swz) << 2)];
            v8bf vf[4];
            #pragma unroll
            for (int nh = 0; nh < 4; nh++)
                vf[nh] = *(const v8bf*)(vtp + (size_t)(nh * 16 + cn) * Tc + kb0 + kc);
            acc_l = __builtin_amdgcn_mfma_f32_16x16x32_bf16(pa, vones, acc_l, 0, 0, 0);
            #pragma unroll
            for (int nh = 0; nh < 4; nh++)
                acc_o[nh] = __builtin_amdgcn_mfma_f32_16x16x32_bf16(
                    pa, vf[nh], acc_o[nh], 0, 0, 0);
        }
    }

    // epilogue: normalize + store (row = qw0 + rq*4 + r, col = nh*16 + cn)
    bf16* ob = o + ((size_t)b * Tc + qw0) * Dc + h * HDc;
    #pragma unroll
    for (int r = 0; r < 4; r++) {
        const float invl = 1.0f / acc_l[r];     // diagonal always in band -> l > 0
        #pragma unroll
        for (int nh = 0; nh < 4; nh++)
            ob[(size_t)(rq * 4 + r) * Dc + nh * 16 + cn] = f2b(acc_o[nh][r] * invl);
    }
}

// ---------------------------------------------------------------- launch
extern "C" void kernel_launch(void* const* d_in, const int* in_sizes, int n_in,
                              void* d_out, int out_size, void* d_ws, size_t ws_size,
                              hipStream_t stream)
{
    const float* x     = (const float*)d_in[0];
    const float* inw   = (const float*)d_in[1];
    const float* inb   = (const float*)d_in[2];
    const float* outw  = (const float*)d_in[3];
    const float* outb  = (const float*)d_in[4];
    const float* w1    = (const float*)d_in[5];
    const float* b1    = (const float*)d_in[6];
    const float* w2    = (const float*)d_in[7];
    const float* b2    = (const float*)d_in[8];
    const float* ln1g  = (const float*)d_in[9];
    const float* ln1b  = (const float*)d_in[10];
    const float* ln2g  = (const float*)d_in[11];
    const float* ln2b  = (const float*)d_in[12];
    const int*   winp  = (const int*)d_in[13];
    float* out = (float*)d_out;   // fp32 [8192][768]; holds x1 mid-pipeline

    // Workspace (55.05 MB needed; >=62.9 MB proven available)
    char* ws = (char*)d_ws;
    constexpr size_t A_OFF   = 0;
    constexpr size_t QKV_OFF = (size_t)BTc * Dc * 2;                   // 12582912
    constexpr size_t WA_OFF  = QKV_OFF + 3 * (size_t)BTc * Dc * 2;     // 50331648
    constexpr size_t WS_NEED = WA_OFF + (size_t)(QKVc + Dc) * Dc * 2;  // 55050240
    if (ws_size < WS_NEED) return;

    bf16*  xn     = (bf16*)(ws + A_OFF);            // xn1 / obuf / xn2
    bf16*  qkvb   = (bf16*)(ws + QKV_OFF);          // Qb|Kb|Vt triple
    bf16*  Qb     = qkvb;
    bf16*  Kb     = qkvb + (size_t)BTc * Dc;
    bf16*  Vt     = qkvb + 2 * (size_t)BTc * Dc;
    bf16*  hbuf   = (bf16*)(ws + QKV_OFF);          // phase B
    bf16*  wmlp   = (bf16*)(ws + QKV_OFF + (size_t)BTc * (2 * Dc) * 2);
    bf16*  w1_b   = wmlp;
    bf16*  w2_b   = wmlp + (size_t)MLPc * Dc;
    bf16*  wqkv_b = (bf16*)(ws + WA_OFF);
    bf16*  wout_b = wqkv_b + (size_t)QKVc * Dc;

    constexpr int HALF = MLPc / 2;  // 1536
    constexpr int NQKV4 = QKVc * Dc / 4, NOUT4 = Dc * Dc / 4;
    constexpr int NW14  = MLPc * Dc / 4, NW24  = Dc * MLPc / 4;

    // phase-A weight conversion (one dispatch)
    cvt2_kernel<<<(NQKV4 + NOUT4) / 256, 256, 0, stream>>>(
        inw, wqkv_b, NQKV4, outw, wout_b);

    // 1. LN1 (fp32 x -> bf16 xn)
    ln_kernel<<<BTc, 256, 0, stream>>>(x, ln1g, ln1b, xn);
    // 2. qkv GEMM with split-store epilogue -> Qb(scaled) | Kb | Vt(transposed)
    gemm_bt<EPI_QKV, 128><<<dim3(QKVc / 128, BTc / 128), 256, 0, stream>>>(
        xn, wqkv_b, inb, qkvb, nullptr, nullptr, BTc, QKVc, Dc, Dc, Dc);
    // 3. banded attention (per-wave q-strips, no merge) -> obuf (= xn)
    attn_kernel<<<dim3(Bc * Hc, Tc / 64), 256, 0, stream>>>(Qb, Kb, Vt, xn, winp);
    // phase-B weight conversion (Vt region dead after attention; one dispatch)
    cvt2_kernel<<<(NW14 + NW24) / 256, 256, 0, stream>>>(
        w1, w1_b, NW14, w2, w2_b);
    // 4. out(x1) = x + obuf @ out_w^T + out_b   (fp32, fused residual; TN=64)
    gemm_bt<EPI_RESID_F32, 64><<<dim3(Dc / 64, BTc / 128), 256, 0, stream>>>(
        xn, wout_b, outb, nullptr, out, x, BTc, Dc, Dc, Dc, Dc);
    // 5. LN2 (d_out fp32 -> bf16 xn2)
    ln_kernel<<<BTc, 256, 0, stream>>>(out, ln2g, ln2b, xn);

    // 6/7. MLP in two 1536-wide halves; d_out holds x1, accumulate onto it
    for (int c = 0; c < 2; c++) {
        const bf16* w1c = w1_b + (size_t)c * HALF * Dc;   // rows [c*1536, ..)
        const bf16* w2c = w2_b + (size_t)c * HALF;        // cols [c*1536, ..)
        gemm_bt<EPI_GELU_BF16, 128><<<dim3(HALF / 128, BTc / 128), 256, 0, stream>>>(
            xn, w1c, b1 + c * HALF, hbuf, nullptr, nullptr, BTc, HALF, Dc, Dc, Dc);
        // down-proj: A = hbuf [8192][HALF], TN=64 for occupancy
        gemm_bt<EPI_ACC_F32, 64><<<dim3(Dc / 64, BTc / 128), 256, 0, stream>>>(
            hbuf, w2c, (c == 0) ? b2 : nullptr, nullptr, out, nullptr,
            BTc, Dc, HALF, HALF, MLPc);
    }
}

// Round 2
// 382.027 us; speedup vs baseline: 1.1437x; 1.1437x over previous
//
#include <hip/hip_runtime.h>
#include <hip/hip_bf16.h>

typedef __bf16 bf16;
typedef __bf16 v8bf __attribute__((ext_vector_type(8)));
typedef __bf16 v4bf __attribute__((ext_vector_type(4)));
typedef float  v4f  __attribute__((ext_vector_type(4)));

#define DEVI __device__ __forceinline__

constexpr int Bc   = 4;
constexpr int Tc   = 2048;
constexpr int Dc   = 768;
constexpr int Hc   = 12;
constexpr int HDc  = 64;
constexpr int MLPc = 3072;
constexpr int QKVc = 2304;    // 3*D
constexpr int BTc  = Bc * Tc; // 8192 rows

DEVI float b2f(bf16 x) { return (float)x; }
DEVI bf16  f2b(float x) { return (bf16)x; }

// async global->LDS, 16B per lane; lds dest = wave-uniform base + lane*16
#define GLDS(gp, lp) __builtin_amdgcn_global_load_lds( \
    (const __attribute__((address_space(1))) void*)(gp), \
    (__attribute__((address_space(3))) void*)(lp), 16, 0, 0)

// ---------------------------------------------------------------- fp32 -> bf16 conversion (two arrays per dispatch)
__global__ __launch_bounds__(256) void cvt2_kernel(
    const float* __restrict__ s0, bf16* __restrict__ d0, int n0,
    const float* __restrict__ s1, bf16* __restrict__ d1)
{
    int i = blockIdx.x * 256 + threadIdx.x;
    const float* s; bf16* d; int j;
    if (i < n0) { s = s0; d = d0; j = i; }
    else        { s = s1; d = d1; j = i - n0; }
    float4 v = ((const float4*)s)[j];
    v4bf o = { f2b(v.x), f2b(v.y), f2b(v.z), f2b(v.w) };
    ((v4bf*)d)[j] = o;
}

// ---------------------------------------------------------------- LayerNorm (fp32 in, bf16 out)
__global__ __launch_bounds__(256) void ln_kernel(
    const float* __restrict__ x, const float* __restrict__ g,
    const float* __restrict__ bt, bf16* __restrict__ out)
{
    const int row = blockIdx.x;
    const int t = threadIdx.x;
    const float* xr = x + (size_t)row * Dc;
    float v[3];
    v[0] = xr[t];
    v[1] = xr[t + 256];
    v[2] = xr[t + 512];
    float s = v[0] + v[1] + v[2];
    float s2 = v[0]*v[0] + v[1]*v[1] + v[2]*v[2];
    #pragma unroll
    for (int off = 32; off > 0; off >>= 1) {
        s  += __shfl_down(s, off);
        s2 += __shfl_down(s2, off);
    }
    __shared__ float red[8];
    const int wave = t >> 6, lane = t & 63;
    if (lane == 0) { red[wave] = s; red[4 + wave] = s2; }
    __syncthreads();
    s  = red[0] + red[1] + red[2] + red[3];
    s2 = red[4] + red[5] + red[6] + red[7];
    const float mean = s * (1.0f / Dc);
    const float var  = s2 * (1.0f / Dc) - mean * mean;
    const float rstd = rsqrtf(var + 1e-5f);
    bf16* orow = out + (size_t)row * Dc;
    #pragma unroll
    for (int i = 0; i < 3; i++) {
        int c = t + i * 256;
        orow[c] = f2b((v[i] - mean) * rstd * g[c] + bt[c]);
    }
}

// ---------------------------------------------------------------- GEMM (C = A @ B^T + bias, fused epilogues)
// A: [M][lda] bf16 row-major; Bw: [N rows][ldb] bf16, K columns used.
// TN = 128 (4 waves of 64x64) or 64 (4 waves of 32x64).
// XCD stripe swizzle + XOR LDS swizzle. EPI_QKV (TN=128): split-store Q|K|Vt.
// Q columns are pre-scaled by log2(e)/8 so attention's exp2 needs no mul.
enum { EPI_QKV = 0, EPI_GELU_BF16 = 1, EPI_RESID_F32 = 2, EPI_ACC_F32 = 3 };

template <int EPI, int TN>
__global__ __launch_bounds__(256) void gemm_bt(
    const bf16* __restrict__ A, const bf16* __restrict__ Bw,
    const float* __restrict__ bias,
    bf16* __restrict__ Cb, float* __restrict__ Cf,
    const float* __restrict__ resf,
    int M, int N, int K, int lda, int ldb)
{
    constexpr int MI = (TN == 128) ? 4 : 2;      // 16-row blocks per wave (m)
    __shared__ __align__(16) bf16 sA[128 * 64];
    __shared__ __align__(16) bf16 sB[TN * 64];
    const int t = threadIdx.x, wave = t >> 6, lane = t & 63;
    const int moff = (TN == 128) ? (wave & 1) * 64 : wave * 32;
    const int noff = (TN == 128) ? (wave >> 1) * 64 : 0;
    // XCD stripe swizzle (ny divisible by 8 for all our shapes)
    const int nx = gridDim.x, ny = gridDim.y;
    const int bid = blockIdx.y * nx + blockIdx.x;
    const int xcd = bid & 7, kk = bid >> 3;
    const int m0 = (xcd * (ny >> 3) + kk / nx) * 128;
    const int n0 = (kk % nx) * TN;
    const bf16* Ag = A + (size_t)m0 * lda;
    const bf16* Bg = Bw + (size_t)n0 * ldb;

    v4f acc[MI][4];
    #pragma unroll
    for (int i = 0; i < MI; i++)
        #pragma unroll
        for (int j = 0; j < 4; j++) acc[i][j] = (v4f)(0.0f);

    for (int k0 = 0; k0 < K; k0 += 64) {
        // stage with XOR swizzle: LDS slot c holds global chunk (c&7)^(r&7)
        #pragma unroll
        for (int i = 0; i < 4; i++) {
            int c = i * 256 + t;
            int r = c >> 3, j = (c & 7) ^ (r & 7);
            GLDS(Ag + (size_t)r * lda + k0 + j * 8,
                 &sA[(i * 256 + wave * 64) * 8]);
        }
        #pragma unroll
        for (int i = 0; i < TN / 32; i++) {
            int c = i * 256 + t;
            int r = c >> 3, j = (c & 7) ^ (r & 7);
            GLDS(Bg + (size_t)r * ldb + k0 + j * 8,
                 &sB[(i * 256 + wave * 64) * 8]);
        }
        __syncthreads();
        #pragma unroll
        for (int ks = 0; ks < 2; ks++) {
            const int rq = lane >> 4, rl = lane & 15;
            v8bf a[MI], b[4];
            #pragma unroll
            for (int mi = 0; mi < MI; mi++) {
                const int row = moff + mi * 16 + rl;
                a[mi] = *(const v8bf*)&sA[row * 64 + ((ks * 4 + rq) ^ (row & 7)) * 8];
            }
            #pragma unroll
            for (int ni = 0; ni < 4; ni++) {
                const int row = noff + ni * 16 + rl;
                b[ni] = *(const v8bf*)&sB[row * 64 + ((ks * 4 + rq) ^ (row & 7)) * 8];
            }
            #pragma unroll
            for (int mi = 0; mi < MI; mi++)
                #pragma unroll
                for (int ni = 0; ni < 4; ni++)
                    acc[mi][ni] = __builtin_amdgcn_mfma_f32_16x16x32_bf16(
                        a[mi], b[ni], acc[mi][ni], 0, 0, 0);
        }
        __syncthreads();
    }

    const int rq = lane >> 4, cn = lane & 15;
    #pragma unroll
    for (int mi = 0; mi < MI; mi++)
        #pragma unroll
        for (int ni = 0; ni < 4; ni++) {
            const int col = n0 + noff + ni * 16 + cn;
            const float bv = bias ? bias[col] : 0.0f;
            if constexpr (EPI == EPI_QKV) {
                const int row0 = m0 + moff + mi * 16 + rq * 4;
                if (n0 < 2 * Dc) {
                    bf16* dst = Cb + (col < Dc ? 0 : (size_t)BTc * Dc);
                    const int cadj = col < Dc ? col : col - Dc;
                    const float qs = (col < Dc) ? 0.18033688011112042f : 1.0f;
                    #pragma unroll
                    for (int r = 0; r < 4; r++)
                        dst[(size_t)(row0 + r) * Dc + cadj] = f2b((acc[mi][ni][r] + bv) * qs);
                } else {
                    const int vcol = col - 2 * Dc;
                    const int hh = vcol >> 6, hd = vcol & 63;
                    const int bb = row0 >> 11, t0 = row0 & 2047;
                    v4bf pk;
                    #pragma unroll
                    for (int r = 0; r < 4; r++) pk[r] = f2b(acc[mi][ni][r] + bv);
                    *(v4bf*)(Cb + 2 * (size_t)BTc * Dc +
                             (((size_t)bb * Hc + hh) * HDc + hd) * Tc + t0) = pk;
                }
            } else {
                #pragma unroll
                for (int r = 0; r < 4; r++) {
                    const int row = m0 + moff + mi * 16 + rq * 4 + r;
                    const size_t idx = (size_t)row * N + col;
                    float vv = acc[mi][ni][r] + bv;
                    if constexpr (EPI == EPI_GELU_BF16) {
                        Cb[idx] = f2b(0.5f * vv * (1.0f + erff(vv * 0.70710678118f)));
                    } else if constexpr (EPI == EPI_RESID_F32) {
                        Cf[idx] = vv + resf[idx];
                    } else {  // EPI_ACC_F32: sequential RMW accumulate
                        Cf[idx] = vv + Cf[idx];
                    }
                }
            }
        }
}

// ---------------------------------------------------------------- Banded flash attention, v3
// 4 fully independent waves per block, each owning a 32-row q-strip and
// walking its whole band. Zero __syncthreads, zero merge: row-sum l kept in
// registers (reduced with 2 shfl_xor at the end). Transposed-S (mfma(K,Q))
// so P packs to v4bf -> single ds_write_b64, XOR-swizzled unpadded LDS.
// Grid = 48 x 16 = 768 blocks; __launch_bounds__(256,3) => whole grid
// co-resident (3 blocks/CU), no dispatch rounds. Explicit K-prefetch (next
// subtile issued before PV) + early V issue (before exp) keep 2 load batches
// in flight per wave. Q pre-scaled by log2(e)/8 in the QKV epilogue;
// no-max softmax exact (scores bounded; exp2 clamp 2^30 can't overflow).
__global__ __launch_bounds__(256, 3) void attn_kernel(
    const bf16* __restrict__ Qb, const bf16* __restrict__ Kb,
    const bf16* __restrict__ Vt, bf16* __restrict__ o,
    const int* __restrict__ winp)
{
    const int bh = blockIdx.x, qt = blockIdx.y;
    const int b = bh / Hc, h = bh % Hc;
    const int win = *winp;
    const int t = threadIdx.x, wave = t >> 6, lane = t & 63;
    const int rq = lane >> 4, cn = lane & 15;
    const int qw0 = qt * 128 + wave * 32;        // this wave's 32-row q-strip

    __shared__ __align__(16) bf16 sP[4][32 * 64];
    bf16* const sPw = &sP[wave][0];
    const int swz = (cn & 7) << 1;               // XOR on 8B-chunk index

    const bf16* qp  = Qb + ((size_t)b * Tc) * Dc + h * HDc;
    const bf16* kp  = Kb + ((size_t)b * Tc) * Dc + h * HDc;
    const bf16* vtp = Vt + (size_t)bh * HDc * Tc;

    // Q fragments (B-operand: col=q=cn within tile mi, k = ks*32+rq*8)
    v8bf qf[2][2];
    #pragma unroll
    for (int ks = 0; ks < 2; ks++)
        #pragma unroll
        for (int mi = 0; mi < 2; mi++)
            qf[ks][mi] = *(const v8bf*)(qp + (size_t)(qw0 + mi * 16 + cn) * Dc
                                        + ks * 32 + rq * 8);

    v4f acc_o[2][4];
    #pragma unroll
    for (int mi = 0; mi < 2; mi++)
        #pragma unroll
        for (int nh = 0; nh < 4; nh++) acc_o[mi][nh] = (v4f)(0.0f);
    float l_part[2] = {0.0f, 0.0f};

    // band: aligned 64-wide key subtiles covering [max(0,qw0-win), qw0+31+win]
    const int k_lo = max(0, qw0 - win);
    const int k_hi = min(Tc - 1, qw0 + 31 + win);
    int kb0 = k_lo & ~63;                        // last kb0 = k_hi&~63 <= Tc-64

    // preload K fragments for first subtile (A-operand: row=k=cn in tile kb)
    v8bf kf[2][4];
    #pragma unroll
    for (int ks = 0; ks < 2; ks++)
        #pragma unroll
        for (int kb = 0; kb < 4; kb++)
            kf[ks][kb] = *(const v8bf*)(kp + (size_t)(kb0 + kb * 16 + cn) * Dc
                                        + ks * 32 + rq * 8);

    for (; kb0 <= k_hi; kb0 += 64) {
        // S^T = K Q^T : sf[kb][mi], row k = kb*16+rq*4+r, col q = mi*16+cn
        v4f sf[4][2];
        #pragma unroll
        for (int kb = 0; kb < 4; kb++)
            #pragma unroll
            for (int mi = 0; mi < 2; mi++) sf[kb][mi] = (v4f)(0.0f);
        #pragma unroll
        for (int ks = 0; ks < 2; ks++)
            #pragma unroll
            for (int kb = 0; kb < 4; kb++)
                #pragma unroll
                for (int mi = 0; mi < 2; mi++)
                    sf[kb][mi] = __builtin_amdgcn_mfma_f32_16x16x32_bf16(
                        kf[ks][kb], qf[ks][mi], sf[kb][mi], 0, 0, 0);

        // issue V early: latency hides under exp phase (B-op: col=hd, k)
        v8bf vf[2][4];
        #pragma unroll
        for (int ks = 0; ks < 2; ks++)
            #pragma unroll
            for (int nh = 0; nh < 4; nh++)
                vf[ks][nh] = *(const v8bf*)(vtp + (size_t)(nh * 16 + cn) * Tc
                                            + kb0 + ks * 32 + rq * 8);

        // p = exp2(clamp(sT)); band mask only on edge subtiles; l in regs
        const bool need_mask = (kb0 + 63 - qw0 > win) || (qw0 + 31 - kb0 > win);
        #pragma unroll
        for (int kb = 0; kb < 4; kb++)
            #pragma unroll
            for (int mi = 0; mi < 2; mi++) {
                v4bf pk;
                #pragma unroll
                for (int r = 0; r < 4; r++) {
                    float tt = sf[kb][mi][r];
                    if (need_mask) {
                        int ki = kb0 + kb * 16 + rq * 4 + r;
                        int qi = qw0 + mi * 16 + cn;
                        int dd = qi - ki; dd = dd < 0 ? -dd : dd;
                        tt = (dd > win) ? -INFINITY : tt;
                    }
                    float p = exp2f(fminf(tt, 30.0f));   // masked -> 0
                    l_part[mi] += p;
                    pk[r] = f2b(p);
                }
                *(v4bf*)&sPw[(mi * 16 + cn) * 64 + (((kb * 4 + rq) ^ swz) << 2)] = pk;
            }

        // prefetch next subtile's K during PV
        {
            const int nkb = (kb0 + 64 <= k_hi) ? kb0 + 64 : kb0;
            #pragma unroll
            for (int ks = 0; ks < 2; ks++)
                #pragma unroll
                for (int kb = 0; kb < 4; kb++)
                    kf[ks][kb] = *(const v8bf*)(kp + (size_t)(nkb + kb * 16 + cn) * Dc
                                                + ks * 32 + rq * 8);
        }

        // O += P V  (A-frag: row q = mi*16+cn, k = ks*32+rq*8)
        #pragma unroll
        for (int ks = 0; ks < 2; ks++) {
            v8bf pa[2];
            #pragma unroll
            for (int mi = 0; mi < 2; mi++)
                pa[mi] = *(const v8bf*)&sPw[(mi * 16 + cn) * 64
                                            + (((ks * 8 + rq * 2) ^ swz) << 2)];
            #pragma unroll
            for (int mi = 0; mi < 2; mi++)
                #pragma unroll
                for (int nh = 0; nh < 4; nh++)
                    acc_o[mi][nh] = __builtin_amdgcn_mfma_f32_16x16x32_bf16(
                        pa[mi], vf[ks][nh], acc_o[mi][nh], 0, 0, 0);
        }
    }

    // l: reduce the rq-quarters (lanes +-16/+-32, same cn)
    #pragma unroll
    for (int mi = 0; mi < 2; mi++) {
        l_part[mi] += __shfl_xor(l_part[mi], 16);
        l_part[mi] += __shfl_xor(l_part[mi], 32);
    }

    // epilogue: normalize + store (row = qw0+mi*16+rq*4+r, col = nh*16+cn)
    bf16* ob = o + ((size_t)b * Tc + qw0) * Dc + h * HDc;
    #pragma unroll
    for (int mi = 0; mi < 2; mi++)
        #pragma unroll
        for (int r = 0; r < 4; r++) {
            const float lv = __shfl(l_part[mi], rq * 4 + r);  // l of this row
            const float invl = 1.0f / lv;                     // diag in band -> l>0
            #pragma unroll
            for (int nh = 0; nh < 4; nh++)
                ob[(size_t)(mi * 16 + rq * 4 + r) * Dc + nh * 16 + cn] =
                    f2b(acc_o[mi][nh][r] * invl);
        }
}

// ---------------------------------------------------------------- launch
extern "C" void kernel_launch(void* const* d_in, const int* in_sizes, int n_in,
                              void* d_out, int out_size, void* d_ws, size_t ws_size,
                              hipStream_t stream)
{
    const float* x     = (const float*)d_in[0];
    const float* inw   = (const float*)d_in[1];
    const float* inb   = (const float*)d_in[2];
    const float* outw  = (const float*)d_in[3];
    const float* outb  = (const float*)d_in[4];
    const float* w1    = (const float*)d_in[5];
    const float* b1    = (const float*)d_in[6];
    const float* w2    = (const float*)d_in[7];
    const float* b2    = (const float*)d_in[8];
    const float* ln1g  = (const float*)d_in[9];
    const float* ln1b  = (const float*)d_in[10];
    const float* ln2g  = (const float*)d_in[11];
    const float* ln2b  = (const float*)d_in[12];
    const int*   winp  = (const int*)d_in[13];
    float* out = (float*)d_out;   // fp32 [8192][768]; holds x1 mid-pipeline

    // Workspace (55.05 MB needed; >=62.9 MB proven available)
    char* ws = (char*)d_ws;
    constexpr size_t A_OFF   = 0;
    constexpr size_t QKV_OFF = (size_t)BTc * Dc * 2;                   // 12582912
    constexpr size_t WA_OFF  = QKV_OFF + 3 * (size_t)BTc * Dc * 2;     // 50331648
    constexpr size_t WS_NEED = WA_OFF + (size_t)(QKVc + Dc) * Dc * 2;  // 55050240
    if (ws_size < WS_NEED) return;

    bf16*  xn     = (bf16*)(ws + A_OFF);            // xn1 / obuf / xn2
    bf16*  qkvb   = (bf16*)(ws + QKV_OFF);          // Qb|Kb|Vt triple
    bf16*  Qb     = qkvb;
    bf16*  Kb     = qkvb + (size_t)BTc * Dc;
    bf16*  Vt     = qkvb + 2 * (size_t)BTc * Dc;
    bf16*  hbuf   = (bf16*)(ws + QKV_OFF);          // phase B
    bf16*  wmlp   = (bf16*)(ws + QKV_OFF + (size_t)BTc * (2 * Dc) * 2);
    bf16*  w1_b   = wmlp;
    bf16*  w2_b   = wmlp + (size_t)MLPc * Dc;
    bf16*  wqkv_b = (bf16*)(ws + WA_OFF);
    bf16*  wout_b = wqkv_b + (size_t)QKVc * Dc;

    constexpr int HALF = MLPc / 2;  // 1536
    constexpr int NQKV4 = QKVc * Dc / 4, NOUT4 = Dc * Dc / 4;
    constexpr int NW14  = MLPc * Dc / 4, NW24  = Dc * MLPc / 4;

    // phase-A weight conversion (one dispatch)
    cvt2_kernel<<<(NQKV4 + NOUT4) / 256, 256, 0, stream>>>(
        inw, wqkv_b, NQKV4, outw, wout_b);

    // 1. LN1 (fp32 x -> bf16 xn)
    ln_kernel<<<BTc, 256, 0, stream>>>(x, ln1g, ln1b, xn);
    // 2. qkv GEMM with split-store epilogue -> Qb(scaled) | Kb | Vt(transposed)
    gemm_bt<EPI_QKV, 128><<<dim3(QKVc / 128, BTc / 128), 256, 0, stream>>>(
        xn, wqkv_b, inb, qkvb, nullptr, nullptr, BTc, QKVc, Dc, Dc, Dc);
    // 3. banded attention (independent 32-row q-strips, no merge) -> obuf (= xn)
    attn_kernel<<<dim3(Bc * Hc, Tc / 128), 256, 0, stream>>>(Qb, Kb, Vt, xn, winp);
    // phase-B weight conversion (Vt region dead after attention; one dispatch)
    cvt2_kernel<<<(NW14 + NW24) / 256, 256, 0, stream>>>(
        w1, w1_b, NW14, w2, w2_b);
    // 4. out(x1) = x + obuf @ out_w^T + out_b   (fp32, fused residual; TN=64)
    gemm_bt<EPI_RESID_F32, 64><<<dim3(Dc / 64, BTc / 128), 256, 0, stream>>>(
        xn, wout_b, outb, nullptr, out, x, BTc, Dc, Dc, Dc, Dc);
    // 5. LN2 (d_out fp32 -> bf16 xn2)
    ln_kernel<<<BTc, 256, 0, stream>>>(out, ln2g, ln2b, xn);

    // 6/7. MLP in two 1536-wide halves; d_out holds x1, accumulate onto it
    for (int c = 0; c < 2; c++) {
        const bf16* w1c = w1_b + (size_t)c * HALF * Dc;   // rows [c*1536, ..)
        const bf16* w2c = w2_b + (size_t)c * HALF;        // cols [c*1536, ..)
        gemm_bt<EPI_GELU_BF16, 128><<<dim3(HALF / 128, BTc / 128), 256, 0, stream>>>(
            xn, w1c, b1 + c * HALF, hbuf, nullptr, nullptr, BTc, HALF, Dc, Dc, Dc);
        // down-proj: A = hbuf [8192][HALF], TN=64 for occupancy
        gemm_bt<EPI_ACC_F32, 64><<<dim3(Dc / 64, BTc / 128), 256, 0, stream>>>(
            hbuf, w2c, (c == 0) ? b2 : nullptr, nullptr, out, nullptr,
            BTc, Dc, HALF, HALF, MLPc);
    }
}

// Round 3
// 375.392 us; speedup vs baseline: 1.1639x; 1.0177x over previous
//
#include <hip/hip_runtime.h>
#include <hip/hip_bf16.h>

typedef __bf16 bf16;
typedef __bf16 v8bf __attribute__((ext_vector_type(8)));
typedef __bf16 v4bf __attribute__((ext_vector_type(4)));
typedef float  v4f  __attribute__((ext_vector_type(4)));

#define DEVI __device__ __forceinline__

constexpr int Bc   = 4;
constexpr int Tc   = 2048;
constexpr int Dc   = 768;
constexpr int Hc   = 12;
constexpr int HDc  = 64;
constexpr int MLPc = 3072;
constexpr int QKVc = 2304;    // 3*D
constexpr int BTc  = Bc * Tc; // 8192 rows

DEVI float b2f(bf16 x) { return (float)x; }
DEVI bf16  f2b(float x) { return (bf16)x; }

// async global->LDS, 16B per lane; lds dest = wave-uniform base + lane*16
#define GLDS(gp, lp) __builtin_amdgcn_global_load_lds( \
    (const __attribute__((address_space(1))) void*)(gp), \
    (__attribute__((address_space(3))) void*)(lp), 16, 0, 0)

// ---------------------------------------------------------------- fp32 -> bf16 conversion (two arrays per dispatch)
__global__ __launch_bounds__(256) void cvt2_kernel(
    const float* __restrict__ s0, bf16* __restrict__ d0, int n0,
    const float* __restrict__ s1, bf16* __restrict__ d1)
{
    int i = blockIdx.x * 256 + threadIdx.x;
    const float* s; bf16* d; int j;
    if (i < n0) { s = s0; d = d0; j = i; }
    else        { s = s1; d = d1; j = i - n0; }
    float4 v = ((const float4*)s)[j];
    v4bf o = { f2b(v.x), f2b(v.y), f2b(v.z), f2b(v.w) };
    ((v4bf*)d)[j] = o;
}

// ---------------------------------------------------------------- LayerNorm (fp32 in, bf16 out)
__global__ __launch_bounds__(256) void ln_kernel(
    const float* __restrict__ x, const float* __restrict__ g,
    const float* __restrict__ bt, bf16* __restrict__ out)
{
    const int row = blockIdx.x;
    const int t = threadIdx.x;
    const float* xr = x + (size_t)row * Dc;
    float v[3];
    v[0] = xr[t];
    v[1] = xr[t + 256];
    v[2] = xr[t + 512];
    float s = v[0] + v[1] + v[2];
    float s2 = v[0]*v[0] + v[1]*v[1] + v[2]*v[2];
    #pragma unroll
    for (int off = 32; off > 0; off >>= 1) {
        s  += __shfl_down(s, off);
        s2 += __shfl_down(s2, off);
    }
    __shared__ float red[8];
    const int wave = t >> 6, lane = t & 63;
    if (lane == 0) { red[wave] = s; red[4 + wave] = s2; }
    __syncthreads();
    s  = red[0] + red[1] + red[2] + red[3];
    s2 = red[4] + red[5] + red[6] + red[7];
    const float mean = s * (1.0f / Dc);
    const float var  = s2 * (1.0f / Dc) - mean * mean;
    const float rstd = rsqrtf(var + 1e-5f);
    bf16* orow = out + (size_t)row * Dc;
    #pragma unroll
    for (int i = 0; i < 3; i++) {
        int c = t + i * 256;
        orow[c] = f2b((v[i] - mean) * rstd * g[c] + bt[c]);
    }
}

// ---------------------------------------------------------------- GEMM (C = A @ B^T + bias, fused epilogues)
// A: [M][lda] bf16 row-major; Bw: [N rows][ldb] bf16, K columns used.
// TN = 128 (4 waves of 64x64) or 64 (4 waves of 32x64).
// XCD stripe swizzle + XOR LDS swizzle. EPI_QKV (TN=128): split-store Q|K|Vt.
// Q columns are pre-scaled by log2(e)/8 so attention's exp2 needs no mul.
enum { EPI_QKV = 0, EPI_GELU_BF16 = 1, EPI_RESID_F32 = 2, EPI_ACC_F32 = 3 };

template <int EPI, int TN>
__global__ __launch_bounds__(256) void gemm_bt(
    const bf16* __restrict__ A, const bf16* __restrict__ Bw,
    const float* __restrict__ bias,
    bf16* __restrict__ Cb, float* __restrict__ Cf,
    const float* __restrict__ resf,
    int M, int N, int K, int lda, int ldb)
{
    constexpr int MI = (TN == 128) ? 4 : 2;      // 16-row blocks per wave (m)
    __shared__ __align__(16) bf16 sA[128 * 64];
    __shared__ __align__(16) bf16 sB[TN * 64];
    const int t = threadIdx.x, wave = t >> 6, lane = t & 63;
    const int moff = (TN == 128) ? (wave & 1) * 64 : wave * 32;
    const int noff = (TN == 128) ? (wave >> 1) * 64 : 0;
    // XCD stripe swizzle (ny divisible by 8 for all our shapes)
    const int nx = gridDim.x, ny = gridDim.y;
    const int bid = blockIdx.y * nx + blockIdx.x;
    const int xcd = bid & 7, kk = bid >> 3;
    const int m0 = (xcd * (ny >> 3) + kk / nx) * 128;
    const int n0 = (kk % nx) * TN;
    const bf16* Ag = A + (size_t)m0 * lda;
    const bf16* Bg = Bw + (size_t)n0 * ldb;

    v4f acc[MI][4];
    #pragma unroll
    for (int i = 0; i < MI; i++)
        #pragma unroll
        for (int j = 0; j < 4; j++) acc[i][j] = (v4f)(0.0f);

    for (int k0 = 0; k0 < K; k0 += 64) {
        // stage with XOR swizzle: LDS slot c holds global chunk (c&7)^(r&7)
        #pragma unroll
        for (int i = 0; i < 4; i++) {
            int c = i * 256 + t;
            int r = c >> 3, j = (c & 7) ^ (r & 7);
            GLDS(Ag + (size_t)r * lda + k0 + j * 8,
                 &sA[(i * 256 + wave * 64) * 8]);
        }
        #pragma unroll
        for (int i = 0; i < TN / 32; i++) {
            int c = i * 256 + t;
            int r = c >> 3, j = (c & 7) ^ (r & 7);
            GLDS(Bg + (size_t)r * ldb + k0 + j * 8,
                 &sB[(i * 256 + wave * 64) * 8]);
        }
        __syncthreads();
        #pragma unroll
        for (int ks = 0; ks < 2; ks++) {
            const int rq = lane >> 4, rl = lane & 15;
            v8bf a[MI], b[4];
            #pragma unroll
            for (int mi = 0; mi < MI; mi++) {
                const int row = moff + mi * 16 + rl;
                a[mi] = *(const v8bf*)&sA[row * 64 + ((ks * 4 + rq) ^ (row & 7)) * 8];
            }
            #pragma unroll
            for (int ni = 0; ni < 4; ni++) {
                const int row = noff + ni * 16 + rl;
                b[ni] = *(const v8bf*)&sB[row * 64 + ((ks * 4 + rq) ^ (row & 7)) * 8];
            }
            #pragma unroll
            for (int mi = 0; mi < MI; mi++)
                #pragma unroll
                for (int ni = 0; ni < 4; ni++)
                    acc[mi][ni] = __builtin_amdgcn_mfma_f32_16x16x32_bf16(
                        a[mi], b[ni], acc[mi][ni], 0, 0, 0);
        }
        __syncthreads();
    }

    const int rq = lane >> 4, cn = lane & 15;
    #pragma unroll
    for (int mi = 0; mi < MI; mi++)
        #pragma unroll
        for (int ni = 0; ni < 4; ni++) {
            const int col = n0 + noff + ni * 16 + cn;
            const float bv = bias ? bias[col] : 0.0f;
            if constexpr (EPI == EPI_QKV) {
                const int row0 = m0 + moff + mi * 16 + rq * 4;
                if (n0 < 2 * Dc) {
                    bf16* dst = Cb + (col < Dc ? 0 : (size_t)BTc * Dc);
                    const int cadj = col < Dc ? col : col - Dc;
                    const float qs = (col < Dc) ? 0.18033688011112042f : 1.0f;
                    #pragma unroll
                    for (int r = 0; r < 4; r++)
                        dst[(size_t)(row0 + r) * Dc + cadj] = f2b((acc[mi][ni][r] + bv) * qs);
                } else {
                    const int vcol = col - 2 * Dc;
                    const int hh = vcol >> 6, hd = vcol & 63;
                    const int bb = row0 >> 11, t0 = row0 & 2047;
                    v4bf pk;
                    #pragma unroll
                    for (int r = 0; r < 4; r++) pk[r] = f2b(acc[mi][ni][r] + bv);
                    *(v4bf*)(Cb + 2 * (size_t)BTc * Dc +
                             (((size_t)bb * Hc + hh) * HDc + hd) * Tc + t0) = pk;
                }
            } else {
                #pragma unroll
                for (int r = 0; r < 4; r++) {
                    const int row = m0 + moff + mi * 16 + rq * 4 + r;
                    const size_t idx = (size_t)row * N + col;
                    float vv = acc[mi][ni][r] + bv;
                    if constexpr (EPI == EPI_GELU_BF16) {
                        Cb[idx] = f2b(0.5f * vv * (1.0f + erff(vv * 0.70710678118f)));
                    } else if constexpr (EPI == EPI_RESID_F32) {
                        Cf[idx] = vv + resf[idx];
                    } else {  // EPI_ACC_F32: sequential RMW accumulate
                        Cf[idx] = vv + Cf[idx];
                    }
                }
            }
        }
}

// ---------------------------------------------------------------- Banded flash attention, v4
// Diagnosis r0-r2: all per-wave direct-from-global K/V fragment loads (16
// scattered cache-line segments per VMEM instr, 4x redundant across waves)
// pinned every variant at ~60us -- TA/L2-request bound, not VALU/MFMA/HBM.
// v4: stage K and V tiles into LDS cooperatively (coalesced global_load_lds,
// GEMM-style XOR swizzle, 4 issues per subtile instead of 64 scattered
// loads), keep v3's independent 32-row q-strips, register l, transposed-S
// with single ds_write_b64 P-transpose. Two barriers per subtile; per-wave
// band predicate on edge subtiles. LDS 32KB -> whole 768-block grid
// co-resident at 3 blocks/CU.
__global__ __launch_bounds__(256, 3) void attn_kernel(
    const bf16* __restrict__ Qb, const bf16* __restrict__ Kb,
    const bf16* __restrict__ Vt, bf16* __restrict__ o,
    const int* __restrict__ winp)
{
    const int bh = blockIdx.x, qt = blockIdx.y;
    const int b = bh / Hc, h = bh % Hc;
    const int q0 = qt * 128;
    const int win = *winp;
    const int t = threadIdx.x, wave = t >> 6, lane = t & 63;
    const int rq = lane >> 4, cn = lane & 15;
    const int qw0 = q0 + wave * 32;              // this wave's 32-row q-strip

    __shared__ __align__(16) bf16 sK[64 * 64];
    __shared__ __align__(16) bf16 sV[64 * 64];
    __shared__ __align__(16) bf16 sP[4][32 * 64];
    bf16* const sPw = &sP[wave][0];
    const int swz = (cn & 7) << 1;               // XOR on 8B-chunk index

    const bf16* qp  = Qb + ((size_t)b * Tc) * Dc + h * HDc;
    const bf16* kp  = Kb + ((size_t)b * Tc) * Dc + h * HDc;
    const bf16* vtp = Vt + (size_t)bh * HDc * Tc;

    // Q fragments (B-operand: col=q=cn within tile mi, k = ks*32+rq*8)
    v8bf qf[2][2];
    #pragma unroll
    for (int ks = 0; ks < 2; ks++)
        #pragma unroll
        for (int mi = 0; mi < 2; mi++)
            qf[ks][mi] = *(const v8bf*)(qp + (size_t)(qw0 + mi * 16 + cn) * Dc
                                        + ks * 32 + rq * 8);

    v4f acc_o[2][4];
    #pragma unroll
    for (int mi = 0; mi < 2; mi++)
        #pragma unroll
        for (int nh = 0; nh < 4; nh++) acc_o[mi][nh] = (v4f)(0.0f);
    float l_part[2] = {0.0f, 0.0f};

    // block band (union of 4 strips); per-wave valid range
    const int wlo = max(0, qw0 - win), whi = min(Tc - 1, qw0 + 31 + win);
    const int klo = max(0, q0 - win) & ~63;
    const int khi = min(Tc - 1, q0 + 127 + win);

    for (int kb0 = klo; kb0 <= khi; kb0 += 64) {
        // cooperative stage: K rows [kb0..+64) x 64d, V^T rows [0..64) x keys
        // XOR swizzle: LDS chunk c holds global chunk (c&7)^(r&7)
        #pragma unroll
        for (int i = 0; i < 2; i++) {
            int c = i * 256 + t;
            int r = c >> 3, j = (c & 7) ^ (r & 7);
            GLDS(kp + (size_t)(kb0 + r) * Dc + j * 8,
                 &sK[(i * 256 + wave * 64) * 8]);
            GLDS(vtp + (size_t)r * Tc + kb0 + j * 8,
                 &sV[(i * 256 + wave * 64) * 8]);
        }
        __syncthreads();

        if (kb0 + 63 >= wlo && kb0 <= whi) {
            // S^T = K Q^T : sf[kb][mi], row k = kb*16+rq*4+r, col q = mi*16+cn
            v4f sf[4][2];
            #pragma unroll
            for (int kb = 0; kb < 4; kb++)
                #pragma unroll
                for (int mi = 0; mi < 2; mi++) sf[kb][mi] = (v4f)(0.0f);
            #pragma unroll
            for (int ks = 0; ks < 2; ks++) {
                v8bf kf[4];
                #pragma unroll
                for (int kb = 0; kb < 4; kb++) {
                    const int row = kb * 16 + cn;
                    kf[kb] = *(const v8bf*)&sK[row * 64
                                              + ((ks * 4 + rq) ^ (row & 7)) * 8];
                }
                #pragma unroll
                for (int kb = 0; kb < 4; kb++)
                    #pragma unroll
                    for (int mi = 0; mi < 2; mi++)
                        sf[kb][mi] = __builtin_amdgcn_mfma_f32_16x16x32_bf16(
                            kf[kb], qf[ks][mi], sf[kb][mi], 0, 0, 0);
            }

            // p = exp2(clamp(sT)); band mask only on edge subtiles; l in regs
            const bool need_mask = (kb0 + 63 - qw0 > win) || (qw0 + 31 - kb0 > win);
            #pragma unroll
            for (int kb = 0; kb < 4; kb++)
                #pragma unroll
                for (int mi = 0; mi < 2; mi++) {
                    v4bf pk;
                    #pragma unroll
                    for (int r = 0; r < 4; r++) {
                        float tt = sf[kb][mi][r];
                        if (need_mask) {
                            int ki = kb0 + kb * 16 + rq * 4 + r;
                            int qi = qw0 + mi * 16 + cn;
                            int dd = qi - ki; dd = dd < 0 ? -dd : dd;
                            tt = (dd > win) ? -INFINITY : tt;
                        }
                        float p = exp2f(fminf(tt, 30.0f));   // masked -> 0
                        l_part[mi] += p;
                        pk[r] = f2b(p);
                    }
                    *(v4bf*)&sPw[(mi * 16 + cn) * 64
                                 + (((kb * 4 + rq) ^ swz) << 2)] = pk;
                }

            // O += P V  (A: row q = mi*16+cn; B from sV: row hd = nh*16+cn)
            #pragma unroll
            for (int ks = 0; ks < 2; ks++) {
                v8bf pa[2], vf[4];
                #pragma unroll
                for (int mi = 0; mi < 2; mi++)
                    pa[mi] = *(const v8bf*)&sPw[(mi * 16 + cn) * 64
                                                + (((ks * 8 + rq * 2) ^ swz) << 2)];
                #pragma unroll
                for (int nh = 0; nh < 4; nh++) {
                    const int row = nh * 16 + cn;
                    vf[nh] = *(const v8bf*)&sV[row * 64
                                               + ((ks * 4 + rq) ^ (row & 7)) * 8];
                }
                #pragma unroll
                for (int mi = 0; mi < 2; mi++)
                    #pragma unroll
                    for (int nh = 0; nh < 4; nh++)
                        acc_o[mi][nh] = __builtin_amdgcn_mfma_f32_16x16x32_bf16(
                            pa[mi], vf[ks * 0 + nh], acc_o[mi][nh], 0, 0, 0);
            }
        }
        __syncthreads();
    }

    // l: reduce the rq-quarters (lanes +-16/+-32, same cn)
    #pragma unroll
    for (int mi = 0; mi < 2; mi++) {
        l_part[mi] += __shfl_xor(l_part[mi], 16);
        l_part[mi] += __shfl_xor(l_part[mi], 32);
    }

    // epilogue: normalize + store (row = qw0+mi*16+rq*4+r, col = nh*16+cn)
    bf16* ob = o + ((size_t)b * Tc + qw0) * Dc + h * HDc;
    #pragma unroll
    for (int mi = 0; mi < 2; mi++)
        #pragma unroll
        for (int r = 0; r < 4; r++) {
            const float lv = __shfl(l_part[mi], rq * 4 + r);  // l of this row
            const float invl = 1.0f / lv;                     // diag in band -> l>0
            #pragma unroll
            for (int nh = 0; nh < 4; nh++)
                ob[(size_t)(mi * 16 + rq * 4 + r) * Dc + nh * 16 + cn] =
                    f2b(acc_o[mi][nh][r] * invl);
        }
}

// ---------------------------------------------------------------- launch
extern "C" void kernel_launch(void* const* d_in, const int* in_sizes, int n_in,
                              void* d_out, int out_size, void* d_ws, size_t ws_size,
                              hipStream_t stream)
{
    const float* x     = (const float*)d_in[0];
    const float* inw   = (const float*)d_in[1];
    const float* inb   = (const float*)d_in[2];
    const float* outw  = (const float*)d_in[3];
    const float* outb  = (const float*)d_in[4];
    const float* w1    = (const float*)d_in[5];
    const float* b1    = (const float*)d_in[6];
    const float* w2    = (const float*)d_in[7];
    const float* b2    = (const float*)d_in[8];
    const float* ln1g  = (const float*)d_in[9];
    const float* ln1b  = (const float*)d_in[10];
    const float* ln2g  = (const float*)d_in[11];
    const float* ln2b  = (const float*)d_in[12];
    const int*   winp  = (const int*)d_in[13];
    float* out = (float*)d_out;   // fp32 [8192][768]; holds x1 mid-pipeline

    // Workspace (55.05 MB needed; >=62.9 MB proven available)
    char* ws = (char*)d_ws;
    constexpr size_t A_OFF   = 0;
    constexpr size_t QKV_OFF = (size_t)BTc * Dc * 2;                   // 12582912
    constexpr size_t WA_OFF  = QKV_OFF + 3 * (size_t)BTc * Dc * 2;     // 50331648
    constexpr size_t WS_NEED = WA_OFF + (size_t)(QKVc + Dc) * Dc * 2;  // 55050240
    if (ws_size < WS_NEED) return;

    bf16*  xn     = (bf16*)(ws + A_OFF);            // xn1 / obuf / xn2
    bf16*  qkvb   = (bf16*)(ws + QKV_OFF);          // Qb|Kb|Vt triple
    bf16*  Qb     = qkvb;
    bf16*  Kb     = qkvb + (size_t)BTc * Dc;
    bf16*  Vt     = qkvb + 2 * (size_t)BTc * Dc;
    bf16*  hbuf   = (bf16*)(ws + QKV_OFF);          // phase B
    bf16*  wmlp   = (bf16*)(ws + QKV_OFF + (size_t)BTc * (2 * Dc) * 2);
    bf16*  w1_b   = wmlp;
    bf16*  w2_b   = wmlp + (size_t)MLPc * Dc;
    bf16*  wqkv_b = (bf16*)(ws + WA_OFF);
    bf16*  wout_b = wqkv_b + (size_t)QKVc * Dc;

    constexpr int HALF = MLPc / 2;  // 1536
    constexpr int NQKV4 = QKVc * Dc / 4, NOUT4 = Dc * Dc / 4;
    constexpr int NW14  = MLPc * Dc / 4, NW24  = Dc * MLPc / 4;

    // phase-A weight conversion (one dispatch)
    cvt2_kernel<<<(NQKV4 + NOUT4) / 256, 256, 0, stream>>>(
        inw, wqkv_b, NQKV4, outw, wout_b);

    // 1. LN1 (fp32 x -> bf16 xn)
    ln_kernel<<<BTc, 256, 0, stream>>>(x, ln1g, ln1b, xn);
    // 2. qkv GEMM with split-store epilogue -> Qb(scaled) | Kb | Vt(transposed)
    gemm_bt<EPI_QKV, 128><<<dim3(QKVc / 128, BTc / 128), 256, 0, stream>>>(
        xn, wqkv_b, inb, qkvb, nullptr, nullptr, BTc, QKVc, Dc, Dc, Dc);
    // 3. banded attention (LDS-staged K/V, independent q-strips) -> obuf (= xn)
    attn_kernel<<<dim3(Bc * Hc, Tc / 128), 256, 0, stream>>>(Qb, Kb, Vt, xn, winp);
    // phase-B weight conversion (Vt region dead after attention; one dispatch)
    cvt2_kernel<<<(NW14 + NW24) / 256, 256, 0, stream>>>(
        w1, w1_b, NW14, w2, w2_b);
    // 4. out(x1) = x + obuf @ out_w^T + out_b   (fp32, fused residual; TN=64)
    gemm_bt<EPI_RESID_F32, 64><<<dim3(Dc / 64, BTc / 128), 256, 0, stream>>>(
        xn, wout_b, outb, nullptr, out, x, BTc, Dc, Dc, Dc, Dc);
    // 5. LN2 (d_out fp32 -> bf16 xn2)
    ln_kernel<<<BTc, 256, 0, stream>>>(out, ln2g, ln2b, xn);

    // 6/7. MLP in two 1536-wide halves; d_out holds x1, accumulate onto it
    for (int c = 0; c < 2; c++) {
        const bf16* w1c = w1_b + (size_t)c * HALF * Dc;   // rows [c*1536, ..)
        const bf16* w2c = w2_b + (size_t)c * HALF;        // cols [c*1536, ..)
        gemm_bt<EPI_GELU_BF16, 128><<<dim3(HALF / 128, BTc / 128), 256, 0, stream>>>(
            xn, w1c, b1 + c * HALF, hbuf, nullptr, nullptr, BTc, HALF, Dc, Dc, Dc);
        // down-proj: A = hbuf [8192][HALF], TN=64 for occupancy
        gemm_bt<EPI_ACC_F32, 64><<<dim3(Dc / 64, BTc / 128), 256, 0, stream>>>(
            hbuf, w2c, (c == 0) ? b2 : nullptr, nullptr, out, nullptr,
            BTc, Dc, HALF, HALF, MLPc);
    }
}